// Round 1
// baseline (1952.341 us; speedup 1.0000x reference)
//
#include <hip/hip_runtime.h>
#include <stdint.h>

typedef float4 __attribute__((may_alias)) float4a;
typedef unsigned int u32;
typedef unsigned long long u64;

// ws float layout: [0] loss, [1] sum(ema_cs),
// [16,16+K) e2 | [16+K,+K) counts | [16+2K,+K*64) emb sums | then N u64 slots
#define WS_LOSS 0
#define WS_SEMA 1
#define WS_HDR  16

__global__ void k_sig(float* o, float v) { o[0] = v; }

__device__ __forceinline__ float sq_nofuse(float x) {
  float p = x * x;
  __asm__("" : "+v"(p));   // block ffp-contract fusing (numpy rounds the square)
  return p;
}

// numpy pairwise_sum, n=64 contiguous fp32: 8 accumulators + fixed combine tree.
__device__ __forceinline__ float np_pairwise64(const float* t) {
  float r0 = t[0], r1 = t[1], r2 = t[2], r3 = t[3];
  float r4 = t[4], r5 = t[5], r6 = t[6], r7 = t[7];
  #pragma unroll
  for (int i = 8; i < 64; i += 8) {
    r0 += t[i + 0]; r1 += t[i + 1]; r2 += t[i + 2]; r3 += t[i + 3];
    r4 += t[i + 4]; r5 += t[i + 5]; r6 += t[i + 6]; r7 += t[i + 7];
  }
  return ((r0 + r1) + (r2 + r3)) + ((r4 + r5) + (r6 + r7));
}

__global__ __launch_bounds__(256) void k_prep(const float* __restrict__ cb,
                                              const float* __restrict__ ecs,
                                              float* __restrict__ ws, int K) {
  const int k = blockIdx.x * 256 + threadIdx.x;   // grid covers exactly K rows
  const float* e = cb + ((size_t)k << 6);
  float t[64];
  #pragma unroll
  for (int j = 0; j < 64; ++j) t[j] = sq_nofuse(e[j]);
  ws[WS_HDR + k] = np_pairwise64(t);              // e2[k], np-fp32-exact

  float v = ecs[k];
  #pragma unroll
  for (int o = 32; o; o >>= 1) v += __shfl_xor(v, o, 64);
  if ((threadIdx.x & 63) == 0) atomicAdd(&ws[WS_SEMA], v);
}

// distance scan: 2 z-rows per lane, half of K per block.
// e operand is wave-uniform -> scalar (SGPR) loads straight from L2-resident cb;
// no LDS, no barriers. v_fmac_f32 takes the SGPR directly.
__global__ __launch_bounds__(256, 2) void k_main(const float* __restrict__ z,
                                                 const float* __restrict__ cb,
                                                 const float* __restrict__ e2s,
                                                 u64* __restrict__ slots,
                                                 int N, int K) {
  const int tid = threadIdx.x;
  const int half = blockIdx.x & 1;                // K-half this block scans
  const int rowblk = blockIdx.x >> 1;             // 512 rows per row-block
  const int r0 = rowblk * 512 + tid;
  const int r1 = r0 + 256;
  const int halfK = K >> 1;
  const int kbase = half * halfK;

  float zv0[64], zv1[64];
  {
    const float4a* zr0 = (const float4a*)(z + ((size_t)r0 << 6));
    const float4a* zr1 = (const float4a*)(z + ((size_t)r1 << 6));
    #pragma unroll
    for (int t = 0; t < 16; ++t) {
      const float4 a = zr0[t];
      zv0[4*t] = a.x; zv0[4*t+1] = a.y; zv0[4*t+2] = a.z; zv0[4*t+3] = a.w;
      const float4 b = zr1[t];
      zv1[4*t] = b.x; zv1[4*t+1] = b.y; zv1[4*t+2] = b.z; zv1[4*t+3] = b.w;
    }
  }
  float z20, z21;
  {
    float t[64];
    #pragma unroll
    for (int j = 0; j < 64; ++j) t[j] = sq_nofuse(zv0[j]);
    z20 = np_pairwise64(t);
    #pragma unroll
    for (int j = 0; j < 64; ++j) t[j] = sq_nofuse(zv1[j]);
    z21 = np_pairwise64(t);
  }

  float best0 = 3.0e38f, best1 = 3.0e38f;
  int bk0 = 0, bk1 = 0;

  #pragma unroll 2
  for (int t = 0; t < halfK; t += 2) {
    const int k = kbase + t;
    const float* __restrict__ e0 = cb + ((size_t)k << 6);   // uniform address
    const float* __restrict__ e1 = e0 + 64;
    float g00 = 0.f, g01 = 0.f, g10 = 0.f, g11 = 0.f;
    #pragma unroll
    for (int j = 0; j < 64; ++j) {     // ascending-j fused chains (np/BLAS order)
      const float ej0 = e0[j];
      const float ej1 = e1[j];
      g00 = __builtin_fmaf(ej0, zv0[j], g00);
      g10 = __builtin_fmaf(ej0, zv1[j], g10);
      g01 = __builtin_fmaf(ej1, zv0[j], g01);
      g11 = __builtin_fmaf(ej1, zv1[j], g11);
    }
    const float ea = e2s[k], ebv = e2s[k + 1];
    // row 0, k then k+1 (strict < : first-min-wins)
    const float d00 = __builtin_fmaf(-2.0f, g00, z20 + ea);
    if (d00 < best0) { best0 = d00; bk0 = k; }
    const float d01 = __builtin_fmaf(-2.0f, g01, z20 + ebv);
    if (d01 < best0) { best0 = d01; bk0 = k + 1; }
    // row 1
    const float d10 = __builtin_fmaf(-2.0f, g10, z21 + ea);
    if (d10 < best1) { best1 = d10; bk1 = k; }
    const float d11 = __builtin_fmaf(-2.0f, g11, z21 + ebv);
    if (d11 < best1) { best1 = d11; bk1 = k + 1; }
  }

  // merge halves: smaller d wins; equal d -> smaller k (low 32 bits) = first-win
  atomicMin(&slots[r0], ((u64)__float_as_uint(best0) << 32) | (u32)bk0);
  atomicMin(&slots[r1], ((u64)__float_as_uint(best1) << 32) | (u32)bk1);
}

// epilogue: read winner, write index+quantized, loss, EMA scatter
__global__ __launch_bounds__(256) void k_post(const float* __restrict__ z,
                                              const float* __restrict__ cb,
                                              const u64* __restrict__ slots,
                                              float* __restrict__ ws,
                                              float* __restrict__ o,
                                              int N, int K) {
  const int r = blockIdx.x * 256 + threadIdx.x;
  const int bk = (int)(u32)(slots[r] & 0xFFFFFFFFull);
  const size_t base = (size_t)N << 6;
  o[base + 1 + (size_t)r] = (float)bk;

  const float4a* zr = (const float4a*)(z + ((size_t)r << 6));
  const float4a* qr = (const float4a*)(cb + ((size_t)bk << 6));
  float4a* dst = (float4a*)(o + ((size_t)r << 6));
  float zbuf[64];
  float lsum = 0.f;
  #pragma unroll
  for (int t = 0; t < 16; ++t) {
    const float4 zw = zr[t];
    const float4 qw = qr[t];
    float4 out;
    float d;
    d = zw.x - qw.x; lsum = __builtin_fmaf(d, d, lsum); out.x = zw.x + (qw.x - zw.x);
    d = zw.y - qw.y; lsum = __builtin_fmaf(d, d, lsum); out.y = zw.y + (qw.y - zw.y);
    d = zw.z - qw.z; lsum = __builtin_fmaf(d, d, lsum); out.z = zw.z + (qw.z - zw.z);
    d = zw.w - qw.w; lsum = __builtin_fmaf(d, d, lsum); out.w = zw.w + (qw.w - zw.w);
    dst[t] = out;
    zbuf[4*t] = zw.x; zbuf[4*t+1] = zw.y; zbuf[4*t+2] = zw.z; zbuf[4*t+3] = zw.w;
  }

  #pragma unroll
  for (int s = 32; s; s >>= 1) lsum += __shfl_xor(lsum, s, 64);
  if ((threadIdx.x & 63) == 0) atomicAdd(ws + WS_LOSS, lsum);

  atomicAdd(ws + WS_HDR + K + bk, 1.0f);
  float* emb = ws + WS_HDR + 2 * K + ((size_t)bk << 6);
  #pragma unroll
  for (int j = 0; j < 64; ++j) atomicAdd(emb + j, zbuf[j]);
}

__global__ __launch_bounds__(256) void k_fin(const float* __restrict__ ecs,
                                             const float* __restrict__ ees,
                                             const float* __restrict__ ws,
                                             float* __restrict__ o,
                                             int N, int K, float lossmul) {
  const int KD = K << 6;
  const int idx = blockIdx.x * 256 + threadIdx.x;
  if (idx >= KD) return;
  const int k = idx >> 6;
  const int j = idx & 63;
  const size_t base = (size_t)N << 6;

  const float n = 0.99f * ws[WS_SEMA] + 0.01f * (float)N;
  const float cs_new = 0.99f * ecs[k] + 0.01f * ws[WS_HDR + K + k];
  const float smoothed = (cs_new + 1e-5f) / (n + (float)K * 1e-5f) * n;
  const float es_new = 0.99f * ees[idx] + 0.01f * ws[WS_HDR + 2 * K + idx];

  const size_t es_base = base + 1 + (size_t)N + (size_t)K;
  o[es_base + (size_t)idx] = es_new;
  o[es_base + (size_t)KD + (size_t)idx] = es_new / smoothed;
  if (j == 0)   o[base + 1 + (size_t)N + (size_t)k] = cs_new;
  if (idx == 0) o[base] = ws[WS_LOSS] * lossmul;
}

extern "C" void kernel_launch(void* const* d_in, const int* in_sizes, int n_in,
                              void* d_out, int out_size, void* d_ws, size_t ws_size,
                              hipStream_t stream) {
  float* o = (float*)d_out;
  const float* z   = (const float*)d_in[0];
  const float* cb  = (const float*)d_in[1];
  const float* ecs = (const float*)d_in[2];
  const float* ees = (const float*)d_in[3];
  float* ws = (float*)d_ws;

  const long long ND  = (n_in > 0) ? (long long)in_sizes[0] : 0;
  const long long KD  = (n_in > 1) ? (long long)in_sizes[1] : 0;
  const long long K   = (n_in > 2) ? (long long)in_sizes[2] : 0;
  const long long KD2 = (n_in > 3) ? (long long)in_sizes[3] : 0;
  const long long D   = (K > 0) ? KD / K : 0;
  const long long N   = (D > 0) ? ND / D : 0;

  const long long ws_floats = 16 + 2 * K + KD + 2 * N;  // slots = N u64 at tail

  float sig = 0.f;
  if (n_in != 4)                          sig = 1e4f * (float)n_in;
  else if (K <= 0 || KD % K != 0)         sig = 2.5e7f;
  else if (D != 64)                       sig = 1e7f + 1e4f * (float)D;
  else if (KD2 != KD)                     sig = 2e7f;
  else if (ND % 64 != 0 || N % 512 != 0)  sig = 3e7f;
  else if (K % 256 != 0)                  sig = 5e7f;
  else if ((long long)out_size != ND + 1 + N + K + 2 * KD)
                                          sig = (float)out_size;
  else if (ws_size < (size_t)ws_floats * sizeof(float))
                                          sig = 7e6f;
  if (sig != 0.f) { k_sig<<<1, 1, 0, stream>>>(o, sig); return; }

  u64* slots = (u64*)(ws + 16 + 2 * K + KD);      // 8-byte aligned offset
  const float lossmul = (float)(0.25 / (double)ND);

  hipMemsetAsync(ws, 0, (size_t)(16 + 2 * K + KD) * sizeof(float), stream);
  hipMemsetAsync(slots, 0xFF, (size_t)N * sizeof(u64), stream);
  k_prep<<<(int)(K / 256), 256, 0, stream>>>(cb, ecs, ws, (int)K);
  k_main<<<(int)(2 * (N / 512)), 256, 0, stream>>>(z, cb, ws + WS_HDR, slots, (int)N, (int)K);
  k_post<<<(int)(N / 256), 256, 0, stream>>>(z, cb, slots, ws, o, (int)N, (int)K);
  k_fin<<<(int)(KD / 256), 256, 0, stream>>>(ecs, ees, ws, o, (int)N, (int)K, lossmul);
}

// Round 2
// 1665.971 us; speedup vs baseline: 1.1719x; 1.1719x over previous
//
#include <hip/hip_runtime.h>
#include <stdint.h>

typedef float4 __attribute__((may_alias)) float4a;
typedef unsigned int u32;
typedef unsigned long long u64;

// ws float layout: [0] loss, [1] sum(ema_cs),
// [16,16+K) e2 | [16+K,+K) counts | [16+2K,+K*64) emb sums | then N u64 slots
#define WS_LOSS 0
#define WS_SEMA 1
#define WS_HDR  16
#define TK 64

__global__ void k_sig(float* o, float v) { o[0] = v; }

__device__ __forceinline__ float sq_nofuse(float x) {
  float p = x * x;
  __asm__("" : "+v"(p));   // block ffp-contract fusing (numpy rounds the square)
  return p;
}

// numpy pairwise_sum, n=64 contiguous fp32: 8 accumulators + fixed combine tree.
__device__ __forceinline__ float np_pairwise64(const float* t) {
  float r0 = t[0], r1 = t[1], r2 = t[2], r3 = t[3];
  float r4 = t[4], r5 = t[5], r6 = t[6], r7 = t[7];
  #pragma unroll
  for (int i = 8; i < 64; i += 8) {
    r0 += t[i + 0]; r1 += t[i + 1]; r2 += t[i + 2]; r3 += t[i + 3];
    r4 += t[i + 4]; r5 += t[i + 5]; r6 += t[i + 6]; r7 += t[i + 7];
  }
  return ((r0 + r1) + (r2 + r3)) + ((r4 + r5) + (r6 + r7));
}

// async 16B-per-lane DMA: global -> LDS (wave-uniform LDS base + lane*16)
__device__ __forceinline__ void dma16(const float* g, float* l) {
  __builtin_amdgcn_global_load_lds(
      (const __attribute__((address_space(1))) unsigned int*)g,
      (__attribute__((address_space(3))) unsigned int*)l,
      16, 0, 0);
}

__global__ __launch_bounds__(256) void k_prep(const float* __restrict__ cb,
                                              const float* __restrict__ ecs,
                                              float* __restrict__ ws, int K) {
  const int k = blockIdx.x * 256 + threadIdx.x;   // grid covers exactly K rows
  const float* e = cb + ((size_t)k << 6);
  float t[64];
  #pragma unroll
  for (int j = 0; j < 64; ++j) t[j] = sq_nofuse(e[j]);
  ws[WS_HDR + k] = np_pairwise64(t);              // e2[k], np-fp32-exact

  float v = ecs[k];
  #pragma unroll
  for (int o = 32; o; o >>= 1) v += __shfl_xor(v, o, 64);
  if ((threadIdx.x & 63) == 0) atomicAdd(&ws[WS_SEMA], v);
}

// distance scan: 1 z-row per lane, half of K per block, 4 waves/SIMD.
// e-tiles staged via async global_load_lds double-buffer; e2 via uniform L1 loads.
__global__ __launch_bounds__(256, 4) void k_main(const float* __restrict__ z,
                                                 const float* __restrict__ cb,
                                                 const float* __restrict__ e2s,
                                                 u64* __restrict__ slots,
                                                 int N, int K) {
  __shared__ float se[2][TK * 64];

  const int tid = threadIdx.x;
  const int lane = tid & 63;
  const int wave = tid >> 6;
  const int half = blockIdx.x & 1;                // K-half this block scans
  const int rowblk = blockIdx.x >> 1;             // 256 rows per row-block
  const int r = rowblk * 256 + tid;
  const int halfK = K >> 1;
  const int kbase = half * halfK;

  float zv[64];
  {
    const float4a* zr = (const float4a*)(z + ((size_t)r << 6));
    #pragma unroll
    for (int t = 0; t < 16; ++t) {
      const float4 a = zr[t];
      zv[4*t] = a.x; zv[4*t+1] = a.y; zv[4*t+2] = a.z; zv[4*t+3] = a.w;
    }
  }
  float z2;
  {
    float t[64];
    #pragma unroll
    for (int j = 0; j < 64; ++j) t[j] = sq_nofuse(zv[j]);
    z2 = np_pairwise64(t);
  }

  const int nt = halfK / TK;
  const int seg = wave * 4;                       // 4 x 1KB segments per wave
  {  // prologue: DMA tile 0 into buffer 0
    const float* src = cb + ((size_t)kbase << 6) + (size_t)seg * 256 + lane * 4;
    float* dst = se[0] + seg * 256;
    #pragma unroll
    for (int c = 0; c < 4; ++c) dma16(src + c * 256, dst + c * 256);
  }

  float best = 3.0e38f;
  int bk = 0;

  for (int t = 0; t < nt; ++t) {
    const int b = t & 1;
    __syncthreads();   // implicit vmcnt(0) drain: buf[b] DMA (issued long ago) done

    if (t + 1 < nt) {  // issue next tile's DMA into the other buffer
      const float* src = cb + ((size_t)(kbase + (t + 1) * TK) << 6)
                            + (size_t)seg * 256 + lane * 4;
      float* dst = se[b ^ 1] + seg * 256;
      #pragma unroll
      for (int c = 0; c < 4; ++c) dma16(src + c * 256, dst + c * 256);
    }

    const float* __restrict__ eb = se[b];
    const int k0 = kbase + t * TK;
    #pragma unroll 1
    for (int kk = 0; kk < TK; kk += 4) {
      const float* e0 = eb + (kk << 6);
      float g0 = 0.f, g1 = 0.f, g2 = 0.f, g3 = 0.f;
      #pragma unroll
      for (int j = 0; j < 64; ++j) {   // ascending-j fused chains (np/BLAS order)
        const float zj = zv[j];
        g0 = __builtin_fmaf(e0[j],       zj, g0);
        g1 = __builtin_fmaf(e0[64 + j],  zj, g1);
        g2 = __builtin_fmaf(e0[128 + j], zj, g2);
        g3 = __builtin_fmaf(e0[192 + j], zj, g3);
      }
      const float4 e2v = *(const float4a*)(e2s + k0 + kk);  // uniform, L1-hot
      float d;
      // ascending k, strict < : first-min-wins
      d = __builtin_fmaf(-2.0f, g0, z2 + e2v.x); if (d < best) { best = d; bk = k0 + kk; }
      d = __builtin_fmaf(-2.0f, g1, z2 + e2v.y); if (d < best) { best = d; bk = k0 + kk + 1; }
      d = __builtin_fmaf(-2.0f, g2, z2 + e2v.z); if (d < best) { best = d; bk = k0 + kk + 2; }
      d = __builtin_fmaf(-2.0f, g3, z2 + e2v.w); if (d < best) { best = d; bk = k0 + kk + 3; }
    }
  }

  // merge halves: smaller d wins; equal d -> smaller k (low 32 bits) = first-win
  atomicMin(&slots[r], ((u64)__float_as_uint(best) << 32) | (u32)bk);
}

// epilogue: read winner, write index+quantized, loss, EMA scatter
__global__ __launch_bounds__(256) void k_post(const float* __restrict__ z,
                                              const float* __restrict__ cb,
                                              const u64* __restrict__ slots,
                                              float* __restrict__ ws,
                                              float* __restrict__ o,
                                              int N, int K) {
  const int r = blockIdx.x * 256 + threadIdx.x;
  const int bk = (int)(u32)(slots[r] & 0xFFFFFFFFull);
  const size_t base = (size_t)N << 6;
  o[base + 1 + (size_t)r] = (float)bk;

  const float4a* zr = (const float4a*)(z + ((size_t)r << 6));
  const float4a* qr = (const float4a*)(cb + ((size_t)bk << 6));
  float4a* dst = (float4a*)(o + ((size_t)r << 6));
  float zbuf[64];
  float lsum = 0.f;
  #pragma unroll
  for (int t = 0; t < 16; ++t) {
    const float4 zw = zr[t];
    const float4 qw = qr[t];
    float4 out;
    float d;
    d = zw.x - qw.x; lsum = __builtin_fmaf(d, d, lsum); out.x = zw.x + (qw.x - zw.x);
    d = zw.y - qw.y; lsum = __builtin_fmaf(d, d, lsum); out.y = zw.y + (qw.y - zw.y);
    d = zw.z - qw.z; lsum = __builtin_fmaf(d, d, lsum); out.z = zw.z + (qw.z - zw.z);
    d = zw.w - qw.w; lsum = __builtin_fmaf(d, d, lsum); out.w = zw.w + (qw.w - zw.w);
    dst[t] = out;
    zbuf[4*t] = zw.x; zbuf[4*t+1] = zw.y; zbuf[4*t+2] = zw.z; zbuf[4*t+3] = zw.w;
  }

  #pragma unroll
  for (int s = 32; s; s >>= 1) lsum += __shfl_xor(lsum, s, 64);
  if ((threadIdx.x & 63) == 0) atomicAdd(ws + WS_LOSS, lsum);

  atomicAdd(ws + WS_HDR + K + bk, 1.0f);
  float* emb = ws + WS_HDR + 2 * K + ((size_t)bk << 6);
  #pragma unroll
  for (int j = 0; j < 64; ++j) atomicAdd(emb + j, zbuf[j]);
}

__global__ __launch_bounds__(256) void k_fin(const float* __restrict__ ecs,
                                             const float* __restrict__ ees,
                                             const float* __restrict__ ws,
                                             float* __restrict__ o,
                                             int N, int K, float lossmul) {
  const int KD = K << 6;
  const int idx = blockIdx.x * 256 + threadIdx.x;
  if (idx >= KD) return;
  const int k = idx >> 6;
  const int j = idx & 63;
  const size_t base = (size_t)N << 6;

  const float n = 0.99f * ws[WS_SEMA] + 0.01f * (float)N;
  const float cs_new = 0.99f * ecs[k] + 0.01f * ws[WS_HDR + K + k];
  const float smoothed = (cs_new + 1e-5f) / (n + (float)K * 1e-5f) * n;
  const float es_new = 0.99f * ees[idx] + 0.01f * ws[WS_HDR + 2 * K + idx];

  const size_t es_base = base + 1 + (size_t)N + (size_t)K;
  o[es_base + (size_t)idx] = es_new;
  o[es_base + (size_t)KD + (size_t)idx] = es_new / smoothed;
  if (j == 0)   o[base + 1 + (size_t)N + (size_t)k] = cs_new;
  if (idx == 0) o[base] = ws[WS_LOSS] * lossmul;
}

extern "C" void kernel_launch(void* const* d_in, const int* in_sizes, int n_in,
                              void* d_out, int out_size, void* d_ws, size_t ws_size,
                              hipStream_t stream) {
  float* o = (float*)d_out;
  const float* z   = (const float*)d_in[0];
  const float* cb  = (const float*)d_in[1];
  const float* ecs = (const float*)d_in[2];
  const float* ees = (const float*)d_in[3];
  float* ws = (float*)d_ws;

  const long long ND  = (n_in > 0) ? (long long)in_sizes[0] : 0;
  const long long KD  = (n_in > 1) ? (long long)in_sizes[1] : 0;
  const long long K   = (n_in > 2) ? (long long)in_sizes[2] : 0;
  const long long KD2 = (n_in > 3) ? (long long)in_sizes[3] : 0;
  const long long D   = (K > 0) ? KD / K : 0;
  const long long N   = (D > 0) ? ND / D : 0;

  const long long ws_floats = 16 + 2 * K + KD + 2 * N;  // slots = N u64 at tail

  float sig = 0.f;
  if (n_in != 4)                          sig = 1e4f * (float)n_in;
  else if (K <= 0 || KD % K != 0)         sig = 2.5e7f;
  else if (D != 64)                       sig = 1e7f + 1e4f * (float)D;
  else if (KD2 != KD)                     sig = 2e7f;
  else if (ND % 64 != 0 || N % 512 != 0)  sig = 3e7f;
  else if (K % 256 != 0)                  sig = 5e7f;
  else if ((long long)out_size != ND + 1 + N + K + 2 * KD)
                                          sig = (float)out_size;
  else if (ws_size < (size_t)ws_floats * sizeof(float))
                                          sig = 7e6f;
  if (sig != 0.f) { k_sig<<<1, 1, 0, stream>>>(o, sig); return; }

  u64* slots = (u64*)(ws + 16 + 2 * K + KD);      // 8-byte aligned offset
  const float lossmul = (float)(0.25 / (double)ND);

  hipMemsetAsync(ws, 0, (size_t)(16 + 2 * K + KD) * sizeof(float), stream);
  hipMemsetAsync(slots, 0xFF, (size_t)N * sizeof(u64), stream);
  k_prep<<<(int)(K / 256), 256, 0, stream>>>(cb, ecs, ws, (int)K);
  k_main<<<(int)(2 * (N / 256)), 256, 0, stream>>>(z, cb, ws + WS_HDR, slots, (int)N, (int)K);
  k_post<<<(int)(N / 256), 256, 0, stream>>>(z, cb, slots, ws, o, (int)N, (int)K);
  k_fin<<<(int)(KD / 256), 256, 0, stream>>>(ecs, ees, ws, o, (int)N, (int)K, lossmul);
}

// Round 3
// 1600.462 us; speedup vs baseline: 1.2199x; 1.0409x over previous
//
#include <hip/hip_runtime.h>
#include <stdint.h>

typedef float4 __attribute__((may_alias)) float4a;
typedef float2 __attribute__((may_alias)) float2a;
typedef unsigned int u32;
typedef unsigned long long u64;

// ws float layout: [0] loss, [1] sum(ema_cs),
// [16,16+K) e2 | [16+K,+K) counts | [16+2K,+K*64) emb sums | then N u64 slots
#define WS_LOSS 0
#define WS_SEMA 1
#define WS_HDR  16
#define TK 64

__global__ void k_sig(float* o, float v) { o[0] = v; }

__device__ __forceinline__ float sq_nofuse(float x) {
  float p = x * x;
  __asm__("" : "+v"(p));   // block ffp-contract fusing (numpy rounds the square)
  return p;
}

// numpy pairwise_sum of squares, n=64 contiguous fp32: 8 accumulators + fixed
// combine tree, STREAMING (only ~16 live temps, no t[64] array -> no spill).
__device__ __forceinline__ float z2_np64(const float* v) {
  float r0 = sq_nofuse(v[0]), r1 = sq_nofuse(v[1]);
  float r2 = sq_nofuse(v[2]), r3 = sq_nofuse(v[3]);
  float r4 = sq_nofuse(v[4]), r5 = sq_nofuse(v[5]);
  float r6 = sq_nofuse(v[6]), r7 = sq_nofuse(v[7]);
  #pragma unroll
  for (int i = 8; i < 64; i += 8) {
    r0 += sq_nofuse(v[i + 0]); r1 += sq_nofuse(v[i + 1]);
    r2 += sq_nofuse(v[i + 2]); r3 += sq_nofuse(v[i + 3]);
    r4 += sq_nofuse(v[i + 4]); r5 += sq_nofuse(v[i + 5]);
    r6 += sq_nofuse(v[i + 6]); r7 += sq_nofuse(v[i + 7]);
  }
  return ((r0 + r1) + (r2 + r3)) + ((r4 + r5) + (r6 + r7));
}

// async 16B-per-lane DMA: global -> LDS (wave-uniform LDS base + lane*16)
__device__ __forceinline__ void dma16(const float* g, float* l) {
  __builtin_amdgcn_global_load_lds(
      (const __attribute__((address_space(1))) unsigned int*)g,
      (__attribute__((address_space(3))) unsigned int*)l,
      16, 0, 0);
}

__global__ __launch_bounds__(256) void k_prep(const float* __restrict__ cb,
                                              const float* __restrict__ ecs,
                                              float* __restrict__ ws, int K) {
  const int k = blockIdx.x * 256 + threadIdx.x;   // grid covers exactly K rows
  const float* e = cb + ((size_t)k << 6);
  ws[WS_HDR + k] = z2_np64(e);                    // e2[k], np-fp32-exact

  float v = ecs[k];
  #pragma unroll
  for (int o = 32; o; o >>= 1) v += __shfl_xor(v, o, 64);
  if ((threadIdx.x & 63) == 0) atomicAdd(&ws[WS_SEMA], v);
}

// distance scan: 2 z-rows per lane, quarter of K per block, 3 waves/SIMD.
// e-tiles staged via async global_load_lds double-buffer; e2 via uniform loads.
__global__ __launch_bounds__(256, 3) void k_main(const float* __restrict__ z,
                                                 const float* __restrict__ cb,
                                                 const float* __restrict__ e2s,
                                                 u64* __restrict__ slots,
                                                 int N, int K) {
  __shared__ float se[2][TK * 64];

  const int tid = threadIdx.x;
  const int lane = tid & 63;
  const int wave = tid >> 6;
  const int quarter = blockIdx.x & 3;             // K-quarter this block scans
  const int rowblk = blockIdx.x >> 2;             // 512 rows per row-block
  const int r0 = rowblk * 512 + tid;
  const int r1 = r0 + 256;
  const int qK = K >> 2;
  const int kbase = quarter * qK;

  float zv0[64], zv1[64];
  {
    const float4a* zr0 = (const float4a*)(z + ((size_t)r0 << 6));
    const float4a* zr1 = (const float4a*)(z + ((size_t)r1 << 6));
    #pragma unroll
    for (int t = 0; t < 16; ++t) {
      const float4 a = zr0[t];
      zv0[4*t] = a.x; zv0[4*t+1] = a.y; zv0[4*t+2] = a.z; zv0[4*t+3] = a.w;
      const float4 b = zr1[t];
      zv1[4*t] = b.x; zv1[4*t+1] = b.y; zv1[4*t+2] = b.z; zv1[4*t+3] = b.w;
    }
  }
  const float z20 = z2_np64(zv0);
  const float z21 = z2_np64(zv1);

  const int nt = qK / TK;
  const int seg = wave * 4;                       // 4 x 1KB segments per wave
  {  // prologue: DMA tile 0 into buffer 0
    const float* src = cb + ((size_t)kbase << 6) + (size_t)seg * 256 + lane * 4;
    float* dst = se[0] + seg * 256;
    #pragma unroll
    for (int c = 0; c < 4; ++c) dma16(src + c * 256, dst + c * 256);
  }

  float best0 = 3.0e38f, best1 = 3.0e38f;
  int bk0 = 0, bk1 = 0;

  for (int t = 0; t < nt; ++t) {
    const int b = t & 1;
    __syncthreads();   // implicit vmcnt(0) drain: buf[b] DMA (issued long ago) done

    if (t + 1 < nt) {  // issue next tile's DMA into the other buffer
      const float* src = cb + ((size_t)(kbase + (t + 1) * TK) << 6)
                            + (size_t)seg * 256 + lane * 4;
      float* dst = se[b ^ 1] + seg * 256;
      #pragma unroll
      for (int c = 0; c < 4; ++c) dma16(src + c * 256, dst + c * 256);
    }

    const float* __restrict__ eb = se[b];
    const int k0 = kbase + t * TK;
    for (int kk = 0; kk < TK; kk += 2) {
      const float* e0 = eb + (kk << 6);
      const float* e1 = e0 + 64;
      float g00 = 0.f, g01 = 0.f, g10 = 0.f, g11 = 0.f;
      #pragma unroll
      for (int j = 0; j < 64; ++j) {     // ascending-j fused chains (np/BLAS order)
        const float ej0 = e0[j];
        const float ej1 = e1[j];
        g00 = __builtin_fmaf(ej0, zv0[j], g00);
        g10 = __builtin_fmaf(ej0, zv1[j], g10);
        g01 = __builtin_fmaf(ej1, zv0[j], g01);
        g11 = __builtin_fmaf(ej1, zv1[j], g11);
      }
      const float2 e2v = *(const float2a*)(e2s + k0 + kk);  // uniform, L1-hot
      const float ea = e2v.x, ebv = e2v.y;
      // row 0, k then k+1 (strict < : first-min-wins)
      const float d00 = __builtin_fmaf(-2.0f, g00, z20 + ea);
      if (d00 < best0) { best0 = d00; bk0 = k0 + kk; }
      const float d01 = __builtin_fmaf(-2.0f, g01, z20 + ebv);
      if (d01 < best0) { best0 = d01; bk0 = k0 + kk + 1; }
      // row 1
      const float d10 = __builtin_fmaf(-2.0f, g10, z21 + ea);
      if (d10 < best1) { best1 = d10; bk1 = k0 + kk; }
      const float d11 = __builtin_fmaf(-2.0f, g11, z21 + ebv);
      if (d11 < best1) { best1 = d11; bk1 = k0 + kk + 1; }
    }
  }

  // merge quarters: smaller d wins; equal d -> smaller k (low 32 bits) = first-win
  atomicMin(&slots[r0], ((u64)__float_as_uint(best0) << 32) | (u32)bk0);
  atomicMin(&slots[r1], ((u64)__float_as_uint(best1) << 32) | (u32)bk1);
}

// epilogue: read winner, write index+quantized, loss, EMA scatter
__global__ __launch_bounds__(256) void k_post(const float* __restrict__ z,
                                              const float* __restrict__ cb,
                                              const u64* __restrict__ slots,
                                              float* __restrict__ ws,
                                              float* __restrict__ o,
                                              int N, int K) {
  const int r = blockIdx.x * 256 + threadIdx.x;
  const int bk = (int)(u32)(slots[r] & 0xFFFFFFFFull);
  const size_t base = (size_t)N << 6;
  o[base + 1 + (size_t)r] = (float)bk;

  const float4a* zr = (const float4a*)(z + ((size_t)r << 6));
  const float4a* qr = (const float4a*)(cb + ((size_t)bk << 6));
  float4a* dst = (float4a*)(o + ((size_t)r << 6));
  float zbuf[64];
  float lsum = 0.f;
  #pragma unroll
  for (int t = 0; t < 16; ++t) {
    const float4 zw = zr[t];
    const float4 qw = qr[t];
    float4 out;
    float d;
    d = zw.x - qw.x; lsum = __builtin_fmaf(d, d, lsum); out.x = zw.x + (qw.x - zw.x);
    d = zw.y - qw.y; lsum = __builtin_fmaf(d, d, lsum); out.y = zw.y + (qw.y - zw.y);
    d = zw.z - qw.z; lsum = __builtin_fmaf(d, d, lsum); out.z = zw.z + (qw.z - zw.z);
    d = zw.w - qw.w; lsum = __builtin_fmaf(d, d, lsum); out.w = zw.w + (qw.w - zw.w);
    dst[t] = out;
    zbuf[4*t] = zw.x; zbuf[4*t+1] = zw.y; zbuf[4*t+2] = zw.z; zbuf[4*t+3] = zw.w;
  }

  #pragma unroll
  for (int s = 32; s; s >>= 1) lsum += __shfl_xor(lsum, s, 64);
  if ((threadIdx.x & 63) == 0) atomicAdd(ws + WS_LOSS, lsum);

  atomicAdd(ws + WS_HDR + K + bk, 1.0f);
  float* emb = ws + WS_HDR + 2 * K + ((size_t)bk << 6);
  #pragma unroll
  for (int j = 0; j < 64; ++j) atomicAdd(emb + j, zbuf[j]);
}

__global__ __launch_bounds__(256) void k_fin(const float* __restrict__ ecs,
                                             const float* __restrict__ ees,
                                             const float* __restrict__ ws,
                                             float* __restrict__ o,
                                             int N, int K, float lossmul) {
  const int KD = K << 6;
  const int idx = blockIdx.x * 256 + threadIdx.x;
  if (idx >= KD) return;
  const int k = idx >> 6;
  const int j = idx & 63;
  const size_t base = (size_t)N << 6;

  const float n = 0.99f * ws[WS_SEMA] + 0.01f * (float)N;
  const float cs_new = 0.99f * ecs[k] + 0.01f * ws[WS_HDR + K + k];
  const float smoothed = (cs_new + 1e-5f) / (n + (float)K * 1e-5f) * n;
  const float es_new = 0.99f * ees[idx] + 0.01f * ws[WS_HDR + 2 * K + idx];

  const size_t es_base = base + 1 + (size_t)N + (size_t)K;
  o[es_base + (size_t)idx] = es_new;
  o[es_base + (size_t)KD + (size_t)idx] = es_new / smoothed;
  if (j == 0)   o[base + 1 + (size_t)N + (size_t)k] = cs_new;
  if (idx == 0) o[base] = ws[WS_LOSS] * lossmul;
}

extern "C" void kernel_launch(void* const* d_in, const int* in_sizes, int n_in,
                              void* d_out, int out_size, void* d_ws, size_t ws_size,
                              hipStream_t stream) {
  float* o = (float*)d_out;
  const float* z   = (const float*)d_in[0];
  const float* cb  = (const float*)d_in[1];
  const float* ecs = (const float*)d_in[2];
  const float* ees = (const float*)d_in[3];
  float* ws = (float*)d_ws;

  const long long ND  = (n_in > 0) ? (long long)in_sizes[0] : 0;
  const long long KD  = (n_in > 1) ? (long long)in_sizes[1] : 0;
  const long long K   = (n_in > 2) ? (long long)in_sizes[2] : 0;
  const long long KD2 = (n_in > 3) ? (long long)in_sizes[3] : 0;
  const long long D   = (K > 0) ? KD / K : 0;
  const long long N   = (D > 0) ? ND / D : 0;

  const long long ws_floats = 16 + 2 * K + KD + 2 * N;  // slots = N u64 at tail

  float sig = 0.f;
  if (n_in != 4)                          sig = 1e4f * (float)n_in;
  else if (K <= 0 || KD % K != 0)         sig = 2.5e7f;
  else if (D != 64)                       sig = 1e7f + 1e4f * (float)D;
  else if (KD2 != KD)                     sig = 2e7f;
  else if (ND % 64 != 0 || N % 512 != 0)  sig = 3e7f;
  else if (K % 256 != 0)                  sig = 5e7f;
  else if ((long long)out_size != ND + 1 + N + K + 2 * KD)
                                          sig = (float)out_size;
  else if (ws_size < (size_t)ws_floats * sizeof(float))
                                          sig = 7e6f;
  if (sig != 0.f) { k_sig<<<1, 1, 0, stream>>>(o, sig); return; }

  u64* slots = (u64*)(ws + 16 + 2 * K + KD);      // 8-byte aligned offset
  const float lossmul = (float)(0.25 / (double)ND);

  hipMemsetAsync(ws, 0, (size_t)(16 + 2 * K + KD) * sizeof(float), stream);
  hipMemsetAsync(slots, 0xFF, (size_t)N * sizeof(u64), stream);
  k_prep<<<(int)(K / 256), 256, 0, stream>>>(cb, ecs, ws, (int)K);
  k_main<<<(int)(4 * (N / 512)), 256, 0, stream>>>(z, cb, ws + WS_HDR, slots, (int)N, (int)K);
  k_post<<<(int)(N / 256), 256, 0, stream>>>(z, cb, slots, ws, o, (int)N, (int)K);
  k_fin<<<(int)(KD / 256), 256, 0, stream>>>(ecs, ees, ws, o, (int)N, (int)K, lossmul);
}